// Round 12
// baseline (142.944 us; speedup 1.0000x reference)
//
#include <hip/hip_runtime.h>

#define T_IN 1024
#define D_DIM 512
#define T_OUT 1280
#define NPAIR 4096   // 8 * 512

// ---------------------------------------------------------------------------
// K1: transpose (b, t, d) -> (b, d, t), 64x64 LDS tiles.
// Also builds fp64 twiddles tw[m] = (cos, -sin)(2 pi m/1024), m=0..1023,
// in its first 4 (x,0,0) blocks.
// ---------------------------------------------------------------------------
__global__ __launch_bounds__(256) void transpose_kernel(const float* __restrict__ x,
                                                        float* __restrict__ xt,
                                                        double2* __restrict__ tw) {
    __shared__ float tile[64][65];
    const int b  = blockIdx.z;
    const int t0 = blockIdx.y * 64;
    const int d0 = blockIdx.x * 64;
    const int dl = threadIdx.x & 63;
    const int r0 = threadIdx.x >> 6;   // 0..3

    if (blockIdx.x < 4 && blockIdx.y == 0 && blockIdx.z == 0) {
        int m = blockIdx.x * 256 + threadIdx.x;
        double th = (6.283185307179586476925286766559 / 1024.0) * (double)m;
        tw[m] = make_double2(cos(th), -sin(th));
    }

#pragma unroll
    for (int i = 0; i < 16; ++i) {
        int tl = r0 * 16 + i;
        tile[tl][dl] = x[((size_t)b * T_IN + (t0 + tl)) * D_DIM + d0 + dl];
    }
    __syncthreads();
#pragma unroll
    for (int i = 0; i < 16; ++i) {
        int dl2 = r0 * 16 + i;
        xt[((size_t)b * D_DIM + (d0 + dl2)) * T_IN + t0 + dl] = tile[dl][dl2];
    }
}

// ---------------------------------------------------------------------------
// eighth-table twiddle lookup: e^{-2 pi i m/1024}, m in [0, 1024)
// ---------------------------------------------------------------------------
__device__ __forceinline__ double2 TW8(const double2* __restrict__ E, int m) {
    int r = m & 255;
    int q = (m >> 8) & 3;
    double c, s;
    if (r <= 128) { double2 t = E[r];       c = t.x; s = t.y; }
    else          { double2 t = E[256 - r]; c = t.y; s = t.x; }
    double C, S;
    switch (q) {
        case 0:  C = c;  S = s;  break;
        case 1:  C = -s; S = c;  break;
        case 2:  C = -c; S = -s; break;
        default: C = s;  S = -c; break;
    }
    return make_double2(C, -S);
}

// ---------------------------------------------------------------------------
// K2 (fused): per (b,d): stats -> standardize/clip -> even/odd butterfly ->
// 1024-pt real DFT (32x32 Cooley-Tukey, fp64, folded stage 2) -> in-block
// parallel top-32 (block argmax over bit-packed amp^2 keys, 32 rounds) ->
// write sel = (amp, phi, k, cos(2 pi k/1024)) directly.
// ---------------------------------------------------------------------------
__global__ __launch_bounds__(256) void dft_kernel(const float* __restrict__ xt,
                                                  const double2* __restrict__ twg,
                                                  float2* __restrict__ stats,
                                                  float4* __restrict__ sel) {
    __shared__ double2 uni[1024];       // A: xs (1024 dbl); B: S[32][32]; C: spec float2[512]
    __shared__ double2 tw_s[130];       // eighth table E[0..128]
    __shared__ double  red_s[16];
    __shared__ double  mlist_s[32];
    double* xs_s = (double*)uni;

    const int tid  = threadIdx.x;
    const int pair = blockIdx.x;

    const float4 v = reinterpret_cast<const float4*>(xt + (size_t)pair * T_IN)[tid];

    if (tid < 130) {
        double2 t = twg[tid];                 // (cos, -sin)
        tw_s[tid] = make_double2(t.x, -t.y);  // store (cos, +sin)
    }

    // --- stats (fp64, deterministic tree reduce; final sum redundant per-thread) ---
    double sum = (double)v.x + (double)v.y + (double)v.z + (double)v.w;
    double sq  = (double)v.x * v.x + (double)v.y * v.y +
                 (double)v.z * v.z + (double)v.w * v.w;
#pragma unroll
    for (int off = 32; off; off >>= 1) {
        sum += __shfl_down(sum, off);
        sq  += __shfl_down(sq, off);
    }
    const int wv = tid >> 6;
    if ((tid & 63) == 0) { red_s[wv] = sum; red_s[8 + wv] = sq; }
    __syncthreads();
    double mean, stdp;
    {
        double s = red_s[0] + red_s[1] + red_s[2] + red_s[3];
        double q = red_s[8] + red_s[9] + red_s[10] + red_s[11];
        mean = s * (1.0 / 1024.0);
        double var = (q - 1024.0 * mean * mean) * (1.0 / 1023.0);
        var = var > 0.0 ? var : 0.0;
        stdp = sqrt(var) + 1e-8;   // reference: std + 1e-8
        if (tid == 0) stats[pair] = make_float2((float)mean, (float)stdp);
    }
    const double inv = 1.0 / stdp;
    {
        double z0 = ((double)v.x - mean) * inv;
        double z1 = ((double)v.y - mean) * inv;
        double z2 = ((double)v.z - mean) * inv;
        double z3 = ((double)v.w - mean) * inv;
        z0 = fmin(2.0, fmax(-2.0, z0)) + 1e-9;
        z1 = fmin(2.0, fmax(-2.0, z1)) + 1e-9;
        z2 = fmin(2.0, fmax(-2.0, z2)) + 1e-9;
        z3 = fmin(2.0, fmax(-2.0, z3)) + 1e-9;
        xs_s[tid * 4 + 0] = z0;
        xs_s[tid * 4 + 1] = z1;
        xs_s[tid * 4 + 2] = z2;
        xs_s[tid * 4 + 3] = z3;
    }
    __syncthreads();

    // --- in-place even/odd butterfly over t1 (pairs t1 <-> 32-t1, t1=1..15) ---
    {
        int idx = tid;
#pragma unroll
        for (int rr = 0; rr < 2; ++rr) {
            if (idx < 480) {
                int t1p = 1 + (idx >> 5);
                int t2c = idx & 31;
                int ia = t1p * 32 + t2c;
                int ib = (32 - t1p) * 32 + t2c;
                double a = xs_s[ia], b = xs_s[ib];
                xs_s[ia] = a + b;
                xs_s[ib] = a - b;
            }
            idx += 256;
        }
    }
    __syncthreads();

    const int k1 = tid & 31;
    const int g  = tid >> 5;   // 0..7

    // --- stage 1 (into registers) ---
    double2 R0, R1, R2, R3;
    {
        const double2 w = TW8(tw_s, k1 * 32);   // e^{-2 pi i k1/32}
        const double sgn16 = (k1 & 1) ? -1.0 : 1.0;

        double ar0 = xs_s[g]      + sgn16 * xs_s[512 + g];
        double ar1 = xs_s[g + 8]  + sgn16 * xs_s[512 + g + 8];
        double ar2 = xs_s[g + 16] + sgn16 * xs_s[512 + g + 16];
        double ar3 = xs_s[g + 24] + sgn16 * xs_s[512 + g + 24];
        double ai0 = 0, ai1 = 0, ai2 = 0, ai3 = 0;

        double c = w.x, s = w.y;   // t1 = 1
#pragma unroll 5
        for (int t1 = 1; t1 <= 15; ++t1) {
            const double* eb = &xs_s[t1 * 32];
            const double* ob = &xs_s[(32 - t1) * 32];
            ar0 = fma(eb[g], c, ar0);      ai0 = fma(ob[g], s, ai0);
            ar1 = fma(eb[g + 8], c, ar1);  ai1 = fma(ob[g + 8], s, ai1);
            ar2 = fma(eb[g + 16], c, ar2); ai2 = fma(ob[g + 16], s, ai2);
            ar3 = fma(eb[g + 24], c, ar3); ai3 = fma(ob[g + 24], s, ai3);
            double cn = c * w.x - s * w.y;
            double sn = s * w.x + c * w.y;
            c = cn; s = sn;
        }
        {
            double2 tm = TW8(tw_s, g * k1);
            R0 = make_double2(ar0 * tm.x - ai0 * tm.y, ar0 * tm.y + ai0 * tm.x);
        }
        {
            double2 tm = TW8(tw_s, (g + 8) * k1);
            R1 = make_double2(ar1 * tm.x - ai1 * tm.y, ar1 * tm.y + ai1 * tm.x);
        }
        {
            double2 tm = TW8(tw_s, (g + 16) * k1);
            R2 = make_double2(ar2 * tm.x - ai2 * tm.y, ar2 * tm.y + ai2 * tm.x);
        }
        {
            double2 tm = TW8(tw_s, (g + 24) * k1);
            R3 = make_double2(ar3 * tm.x - ai3 * tm.y, ar3 * tm.y + ai3 * tm.x);
        }
    }
    __syncthreads();   // xs reads done -> overwrite union with S

    uni[g * 32 + k1]        = R0;
    uni[(g + 8) * 32 + k1]  = R1;
    uni[(g + 16) * 32 + k1] = R2;
    uni[(g + 24) * 32 + k1] = R3;
    __syncthreads();

    // --- stage 2 (folded): E[t2] = S[t2] + (-1)^g S[t2+16], bins g and g+8
    //     via W32^{t2(g+8)} = W32^{t2 g} * (-i)^{t2}.
    double Ar = 0, Ai = 0, Br = 0, Bi = 0;
    {
        const double2 wa = TW8(tw_s, 32 * g);   // e^{-2 pi i g/32}
        const double sg = (g & 1) ? -1.0 : 1.0;
        double ca = 1.0, sa = 0.0;
#pragma unroll
        for (int u = 0; u < 4; ++u) {
            {
                const int t2 = 4 * u + 0;
                double2 S  = uni[t2 * 32 + k1];
                double2 S2 = uni[(t2 + 16) * 32 + k1];
                double Ex = fma(sg, S2.x, S.x);
                double Ey = fma(sg, S2.y, S.y);
                double P = fma(Ex, ca, -(Ey * sa));
                double Q = fma(Ex, sa,  (Ey * ca));
                Ar += P; Ai += Q; Br += P; Bi += Q;
                double cn = fma(ca, wa.x, -(sa * wa.y));
                double sn = fma(sa, wa.x,  (ca * wa.y));
                ca = cn; sa = sn;
            }
            {
                const int t2 = 4 * u + 1;
                double2 S  = uni[t2 * 32 + k1];
                double2 S2 = uni[(t2 + 16) * 32 + k1];
                double Ex = fma(sg, S2.x, S.x);
                double Ey = fma(sg, S2.y, S.y);
                double P = fma(Ex, ca, -(Ey * sa));
                double Q = fma(Ex, sa,  (Ey * ca));
                Ar += P; Ai += Q; Br += Q; Bi -= P;
                double cn = fma(ca, wa.x, -(sa * wa.y));
                double sn = fma(sa, wa.x,  (ca * wa.y));
                ca = cn; sa = sn;
            }
            {
                const int t2 = 4 * u + 2;
                double2 S  = uni[t2 * 32 + k1];
                double2 S2 = uni[(t2 + 16) * 32 + k1];
                double Ex = fma(sg, S2.x, S.x);
                double Ey = fma(sg, S2.y, S.y);
                double P = fma(Ex, ca, -(Ey * sa));
                double Q = fma(Ex, sa,  (Ey * ca));
                Ar += P; Ai += Q; Br -= P; Bi -= Q;
                double cn = fma(ca, wa.x, -(sa * wa.y));
                double sn = fma(sa, wa.x,  (ca * wa.y));
                ca = cn; sa = sn;
            }
            {
                const int t2 = 4 * u + 3;
                double2 S  = uni[t2 * 32 + k1];
                double2 S2 = uni[(t2 + 16) * 32 + k1];
                double Ex = fma(sg, S2.x, S.x);
                double Ey = fma(sg, S2.y, S.y);
                double P = fma(Ex, ca, -(Ey * sa));
                double Q = fma(Ex, sa,  (Ey * ca));
                Ar += P; Ai += Q; Br -= Q; Bi += P;
                double cn = fma(ca, wa.x, -(sa * wa.y));
                double sn = fma(sa, wa.x,  (ca * wa.y));
                ca = cn; sa = sn;
            }
        }
    }
    const int ka = k1 + 32 * g;          // == tid
    const int kb = k1 + 32 * (g + 8);    // == tid + 256

    // amp^2 keys, (1023-k) packed in low 10 mantissa bits (lax.top_k tiebreak)
    double keya, keyb;
    {
        double a2a = Ar * Ar + Ai * Ai;
        double a2b = Br * Br + Bi * Bi;
        unsigned long long bba = __double_as_longlong(a2a);
        unsigned long long bbb = __double_as_longlong(a2b);
        keya = __longlong_as_double((bba & ~1023ULL) |
                                    (unsigned long long)(1023 - ka));
        keyb = __longlong_as_double((bbb & ~1023ULL) |
                                    (unsigned long long)(1023 - kb));
        if (ka == 0) keya = -1.0;   // DC excluded
    }

    // park spec in LDS (uni is dead after stage-2 reads)
    __syncthreads();
    float2* spec_f = (float2*)uni;
    spec_f[ka] = make_float2((float)Ar, (float)Ai);
    spec_f[kb] = make_float2((float)Br, (float)Bi);

    // --- in-block parallel top-32: 32 rounds of block argmax over keys ---
    for (int r = 0; r < 32; ++r) {
        double lm = fmax(keya, keyb);
#pragma unroll
        for (int off = 1; off < 64; off <<= 1)
            lm = fmax(lm, __shfl_xor(lm, off));
        if ((tid & 63) == 0) red_s[wv] = lm;
        __syncthreads();
        double m = fmax(fmax(red_s[0], red_s[1]), fmax(red_s[2], red_s[3]));
        if (keya == m) keya = -2.0;   // keys unique (index bits) -> exact match
        if (keyb == m) keyb = -2.0;
        if (tid == 0) mlist_s[r] = m;
        __syncthreads();
    }

    // --- tail: 32 lanes decode winners and write sel ---
    if (tid < 32) {
        double m = mlist_s[tid];
        unsigned long long b = __double_as_longlong(m);
        int k = 1023 - (int)(b & 1023ULL);
        float2 sp = spec_f[k];
        float ph = atan2f(sp.y, sp.x);
        double amp = sqrt(m);   // m = amp^2 (packed bits, rel err 2^-43)
        float aout = (float)(2.0 * amp / (1024.0 + 1e-8));
        const float C = 6.28318530717958647692f / 1024.0f;
        float tkc = __cosf((float)k * C);
        sel[(size_t)pair * 32 + tid] = make_float4(aout, ph, (float)k, tkc);
    }
}

// ---------------------------------------------------------------------------
// K3 v6: Chebyshev reconstruction + t-periodicity.
// cos(ang0 + n*kC) via c_{n+1} = 2cos(kC)*c_n - c_{n-1}: 2 fma/term.
// out[t+1024] = out[t] for t<256 (angle periodic mod 2pi, exact).
// Block: 64 d-lanes x 4 waves x 16 t; 16 chunks of 64 t cover t<1024.
// ---------------------------------------------------------------------------
__global__ __launch_bounds__(256) void recon_kernel(const float4* __restrict__ sel,
                                                    const float2* __restrict__ stats,
                                                    float* __restrict__ out) {
    __shared__ float4 sel_s[32][65];
    __shared__ float2 st_s[64];
    const int bid   = blockIdx.x;
    const int chunk = bid & 15;        // 16 chunks x 64 t
    const int dt    = (bid >> 4) & 7;
    const int b     = bid >> 7;
    const int d0    = dt * 64;
    const int tid   = threadIdx.x;
#pragma unroll
    for (int it = 0; it < 8; ++it) {
        int i   = tid + it * 256;
        int j   = i & 31;
        int dls = i >> 5;
        sel_s[j][dls] = sel[((size_t)(b * D_DIM + d0 + dls)) * 32 + j];
    }
    if (tid < 64) st_s[tid] = stats[b * D_DIM + d0 + tid];
    __syncthreads();

    const int dl    = tid & 63;
    const int wvv   = tid >> 6;
    const int tbase = chunk * 64 + wvv * 16;   // < 1024

    float acc[16];
#pragma unroll
    for (int j = 0; j < 16; ++j) acc[j] = 0.0f;

    const float C = 6.28318530717958647692f / 1024.0f;
#pragma unroll 2
    for (int js = 0; js < 32; ++js) {
        float4 tr = sel_s[js][dl];       // (a, phi, k, cos(kC))
        const float a = tr.x;
        int k = (int)tr.z;
        float ck = tr.w;
        float sk = sqrtf(fmaxf(1.0f - ck * ck, 0.0f));   // k in [1,511] -> sin>0
        int mm0 = (k * tbase) & 1023;
        float ang0 = fmaf((float)mm0, C, tr.y);
        float s0, c0;
        __sincosf(ang0, &s0, &c0);
        float c1 = c0 * ck - s0 * sk;
        float K2 = ck + ck;
        acc[0] = fmaf(a, c0, acc[0]);
        acc[1] = fmaf(a, c1, acc[1]);
#pragma unroll
        for (int j = 2; j < 16; ++j) {
            float c2 = fmaf(K2, c1, -c0);
            acc[j] = fmaf(a, c2, acc[j]);
            c0 = c1; c1 = c2;
        }
    }
    const float2 st = st_s[dl];
#pragma unroll
    for (int j = 0; j < 16; ++j) {
        float o = fmaf(acc[j], st.y, st.x);
        int t = tbase + j;
        out[((size_t)b * T_OUT + t) * D_DIM + d0 + dl] = o;
        if (t < 256)
            out[((size_t)b * T_OUT + t + 1024) * D_DIM + d0 + dl] = o;
    }
}

// ---------------------------------------------------------------------------
extern "C" void kernel_launch(void* const* d_in, const int* in_sizes, int n_in,
                              void* d_out, int out_size, void* d_ws, size_t ws_size,
                              hipStream_t stream) {
    const float* x = (const float*)d_in[0];
    float* out = (float*)d_out;
    char* ws = (char*)d_ws;
    const size_t MB = 1024 * 1024;

    // layout (total ~18.1 MB; observed ws >= 39 MB):
    float*   xt    = (float*)ws;                          // 16 MB
    double2* tw    = (double2*)(ws + 16 * MB);            // 16 KB
    float2*  stats = (float2*)(ws + 16 * MB + 65536);     // 32 KB
    float4*  sel   = (float4*)(ws + 16 * MB + 131072);    //  2 MB

    transpose_kernel<<<dim3(8, 16, 8), 256, 0, stream>>>(x, xt, tw);
    dft_kernel<<<NPAIR, 256, 0, stream>>>(xt, tw, stats, sel);
    recon_kernel<<<1024, 256, 0, stream>>>(sel, stats, out);
}

// Round 13
// 87.354 us; speedup vs baseline: 1.6364x; 1.6364x over previous
//
#include <hip/hip_runtime.h>
#include <hip/hip_fp16.h>

#define T_IN 1024
#define D_DIM 512
#define T_OUT 1280
#define NPAIR 4096   // 8 * 512

// ---------------------------------------------------------------------------
// K1: transpose (b, t, d) -> (b, d, t), 64x64 LDS tiles.
// Also builds fp64 twiddles tw[m] = (cos, -sin)(2 pi m/1024), m=0..1023.
// ---------------------------------------------------------------------------
__global__ __launch_bounds__(256) void transpose_kernel(const float* __restrict__ x,
                                                        float* __restrict__ xt,
                                                        double2* __restrict__ tw) {
    __shared__ float tile[64][65];
    const int b  = blockIdx.z;
    const int t0 = blockIdx.y * 64;
    const int d0 = blockIdx.x * 64;
    const int dl = threadIdx.x & 63;
    const int r0 = threadIdx.x >> 6;   // 0..3

    if (blockIdx.x < 4 && blockIdx.y == 0 && blockIdx.z == 0) {
        int m = blockIdx.x * 256 + threadIdx.x;
        double th = (6.283185307179586476925286766559 / 1024.0) * (double)m;
        tw[m] = make_double2(cos(th), -sin(th));
    }

#pragma unroll
    for (int i = 0; i < 16; ++i) {
        int tl = r0 * 16 + i;
        tile[tl][dl] = x[((size_t)b * T_IN + (t0 + tl)) * D_DIM + d0 + dl];
    }
    __syncthreads();
#pragma unroll
    for (int i = 0; i < 16; ++i) {
        int dl2 = r0 * 16 + i;
        xt[((size_t)b * D_DIM + (d0 + dl2)) * T_IN + t0 + dl] = tile[dl][dl2];
    }
}

// ---------------------------------------------------------------------------
// eighth-table twiddle lookup: e^{-2 pi i m/1024}, m in [0, 1024)
// ---------------------------------------------------------------------------
__device__ __forceinline__ double2 TW8(const double2* __restrict__ E, int m) {
    int r = m & 255;
    int q = (m >> 8) & 3;
    double c, s;
    if (r <= 128) { double2 t = E[r];       c = t.x; s = t.y; }
    else          { double2 t = E[256 - r]; c = t.y; s = t.x; }
    double C, S;
    switch (q) {
        case 0:  C = c;  S = s;  break;
        case 1:  C = -s; S = c;  break;
        case 2:  C = -c; S = -s; break;
        default: C = s;  S = -c; break;
    }
    return make_double2(C, -S);
}

// ---------------------------------------------------------------------------
// K2: TWO pairs per block (2x ILP per thread, shared twiddle recurrences).
// Per pair: stats -> standardize/clip -> even/odd butterfly -> 1024-pt real
// DFT (32x32 Cooley-Tukey, fp64, folded stage 2) -> amp^2 keys + half phase.
// ---------------------------------------------------------------------------
__global__ __launch_bounds__(256) void dft_kernel(const float* __restrict__ xt,
                                                  const double2* __restrict__ twg,
                                                  float2* __restrict__ stats,
                                                  double* __restrict__ keys,
                                                  __half* __restrict__ phase) {
    __shared__ double2 uni[2][1024];    // per pair: A = xs (1024 dbl); B = S[32][32]
    __shared__ double2 tw_s[130];       // eighth table E[0..128]
    __shared__ double  red_s[2][16];

    const int tid   = threadIdx.x;
    const int pair0 = blockIdx.x * 2;

    const float4 va = reinterpret_cast<const float4*>(xt + (size_t)pair0 * T_IN)[tid];
    const float4 vb = reinterpret_cast<const float4*>(xt + (size_t)(pair0 + 1) * T_IN)[tid];

    if (tid < 130) {
        double2 t = twg[tid];                 // (cos, -sin)
        tw_s[tid] = make_double2(t.x, -t.y);  // store (cos, +sin)
    }

    // --- stats, both pairs (independent shfl chains -> ILP) ---
    double sum0 = (double)va.x + (double)va.y + (double)va.z + (double)va.w;
    double sq0  = (double)va.x * va.x + (double)va.y * va.y +
                  (double)va.z * va.z + (double)va.w * va.w;
    double sum1 = (double)vb.x + (double)vb.y + (double)vb.z + (double)vb.w;
    double sq1  = (double)vb.x * vb.x + (double)vb.y * vb.y +
                  (double)vb.z * vb.z + (double)vb.w * vb.w;
#pragma unroll
    for (int off = 32; off; off >>= 1) {
        sum0 += __shfl_down(sum0, off);
        sq0  += __shfl_down(sq0, off);
        sum1 += __shfl_down(sum1, off);
        sq1  += __shfl_down(sq1, off);
    }
    const int wv = tid >> 6;
    if ((tid & 63) == 0) {
        red_s[0][wv] = sum0; red_s[0][8 + wv] = sq0;
        red_s[1][wv] = sum1; red_s[1][8 + wv] = sq1;
    }
    __syncthreads();
    double mean[2], inv[2];
#pragma unroll
    for (int p = 0; p < 2; ++p) {
        double s = red_s[p][0] + red_s[p][1] + red_s[p][2] + red_s[p][3];
        double q = red_s[p][8] + red_s[p][9] + red_s[p][10] + red_s[p][11];
        double mn = s * (1.0 / 1024.0);
        double var = (q - 1024.0 * mn * mn) * (1.0 / 1023.0);
        var = var > 0.0 ? var : 0.0;
        double stdp = sqrt(var) + 1e-8;   // reference: std + 1e-8
        if (tid == 0) stats[pair0 + p] = make_float2((float)mn, (float)stdp);
        mean[p] = mn; inv[p] = 1.0 / stdp;
    }
    double* xs0 = (double*)uni[0];
    double* xs1 = (double*)uni[1];
    {
        double z0 = ((double)va.x - mean[0]) * inv[0];
        double z1 = ((double)va.y - mean[0]) * inv[0];
        double z2 = ((double)va.z - mean[0]) * inv[0];
        double z3 = ((double)va.w - mean[0]) * inv[0];
        double y0 = ((double)vb.x - mean[1]) * inv[1];
        double y1 = ((double)vb.y - mean[1]) * inv[1];
        double y2 = ((double)vb.z - mean[1]) * inv[1];
        double y3 = ((double)vb.w - mean[1]) * inv[1];
        xs0[tid * 4 + 0] = fmin(2.0, fmax(-2.0, z0)) + 1e-9;
        xs0[tid * 4 + 1] = fmin(2.0, fmax(-2.0, z1)) + 1e-9;
        xs0[tid * 4 + 2] = fmin(2.0, fmax(-2.0, z2)) + 1e-9;
        xs0[tid * 4 + 3] = fmin(2.0, fmax(-2.0, z3)) + 1e-9;
        xs1[tid * 4 + 0] = fmin(2.0, fmax(-2.0, y0)) + 1e-9;
        xs1[tid * 4 + 1] = fmin(2.0, fmax(-2.0, y1)) + 1e-9;
        xs1[tid * 4 + 2] = fmin(2.0, fmax(-2.0, y2)) + 1e-9;
        xs1[tid * 4 + 3] = fmin(2.0, fmax(-2.0, y3)) + 1e-9;
    }
    __syncthreads();

    // --- in-place even/odd butterfly over t1 (pairs t1 <-> 32-t1), both pairs ---
#pragma unroll
    for (int p = 0; p < 2; ++p) {
        double* xs = p ? xs1 : xs0;
        int idx = tid;
#pragma unroll
        for (int rr = 0; rr < 2; ++rr) {
            if (idx < 480) {
                int t1p = 1 + (idx >> 5);
                int t2c = idx & 31;
                int ia = t1p * 32 + t2c;
                int ib = (32 - t1p) * 32 + t2c;
                double a = xs[ia], b = xs[ib];
                xs[ia] = a + b;
                xs[ib] = a - b;
            }
            idx += 256;
        }
    }
    __syncthreads();

    const int k1 = tid & 31;
    const int g  = tid >> 5;   // 0..7

    // --- stage 1 (into registers), shared twiddle recurrence across pairs ---
    double2 R0[2], R1[2], R2[2], R3[2];
    {
        const double2 w = TW8(tw_s, k1 * 32);   // e^{-2 pi i k1/32}
        const double sgn16 = (k1 & 1) ? -1.0 : 1.0;

        double ar0[2], ar1[2], ar2[2], ar3[2];
        double ai0[2], ai1[2], ai2[2], ai3[2];
#pragma unroll
        for (int p = 0; p < 2; ++p) {
            const double* xs = p ? xs1 : xs0;
            ar0[p] = xs[g]      + sgn16 * xs[512 + g];
            ar1[p] = xs[g + 8]  + sgn16 * xs[512 + g + 8];
            ar2[p] = xs[g + 16] + sgn16 * xs[512 + g + 16];
            ar3[p] = xs[g + 24] + sgn16 * xs[512 + g + 24];
            ai0[p] = 0; ai1[p] = 0; ai2[p] = 0; ai3[p] = 0;
        }

        double c = w.x, s = w.y;   // t1 = 1
#pragma unroll 5
        for (int t1 = 1; t1 <= 15; ++t1) {
#pragma unroll
            for (int p = 0; p < 2; ++p) {
                const double* xs = p ? xs1 : xs0;
                const double* eb = &xs[t1 * 32];
                const double* ob = &xs[(32 - t1) * 32];
                ar0[p] = fma(eb[g], c, ar0[p]);      ai0[p] = fma(ob[g], s, ai0[p]);
                ar1[p] = fma(eb[g + 8], c, ar1[p]);  ai1[p] = fma(ob[g + 8], s, ai1[p]);
                ar2[p] = fma(eb[g + 16], c, ar2[p]); ai2[p] = fma(ob[g + 16], s, ai2[p]);
                ar3[p] = fma(eb[g + 24], c, ar3[p]); ai3[p] = fma(ob[g + 24], s, ai3[p]);
            }
            double cn = c * w.x - s * w.y;
            double sn = s * w.x + c * w.y;
            c = cn; s = sn;
        }
        double2 tm0 = TW8(tw_s, g * k1);
        double2 tm1 = TW8(tw_s, (g + 8) * k1);
        double2 tm2 = TW8(tw_s, (g + 16) * k1);
        double2 tm3 = TW8(tw_s, (g + 24) * k1);
#pragma unroll
        for (int p = 0; p < 2; ++p) {
            R0[p] = make_double2(ar0[p] * tm0.x - ai0[p] * tm0.y,
                                 ar0[p] * tm0.y + ai0[p] * tm0.x);
            R1[p] = make_double2(ar1[p] * tm1.x - ai1[p] * tm1.y,
                                 ar1[p] * tm1.y + ai1[p] * tm1.x);
            R2[p] = make_double2(ar2[p] * tm2.x - ai2[p] * tm2.y,
                                 ar2[p] * tm2.y + ai2[p] * tm2.x);
            R3[p] = make_double2(ar3[p] * tm3.x - ai3[p] * tm3.y,
                                 ar3[p] * tm3.y + ai3[p] * tm3.x);
        }
    }
    __syncthreads();   // xs reads done -> overwrite unions with S

#pragma unroll
    for (int p = 0; p < 2; ++p) {
        uni[p][g * 32 + k1]        = R0[p];
        uni[p][(g + 8) * 32 + k1]  = R1[p];
        uni[p][(g + 16) * 32 + k1] = R2[p];
        uni[p][(g + 24) * 32 + k1] = R3[p];
    }
    __syncthreads();

    // --- stage 2 (folded): E[t2] = S[t2] + (-1)^g S[t2+16], bins g and g+8
    //     via W32^{t2(g+8)} = W32^{t2 g} * (-i)^{t2}; shared recurrence.
    double Ar[2] = {0, 0}, Ai[2] = {0, 0}, Br[2] = {0, 0}, Bi[2] = {0, 0};
    {
        const double2 wa = TW8(tw_s, 32 * g);   // e^{-2 pi i g/32}
        const double sg = (g & 1) ? -1.0 : 1.0;
        double ca = 1.0, sa = 0.0;
#pragma unroll
        for (int u = 0; u < 4; ++u) {
            {
                const int t2 = 4 * u + 0;
#pragma unroll
                for (int p = 0; p < 2; ++p) {
                    double2 S  = uni[p][t2 * 32 + k1];
                    double2 S2 = uni[p][(t2 + 16) * 32 + k1];
                    double Ex = fma(sg, S2.x, S.x);
                    double Ey = fma(sg, S2.y, S.y);
                    double P = fma(Ex, ca, -(Ey * sa));
                    double Q = fma(Ex, sa,  (Ey * ca));
                    Ar[p] += P; Ai[p] += Q; Br[p] += P; Bi[p] += Q;
                }
                double cn = fma(ca, wa.x, -(sa * wa.y));
                double sn = fma(sa, wa.x,  (ca * wa.y));
                ca = cn; sa = sn;
            }
            {
                const int t2 = 4 * u + 1;
#pragma unroll
                for (int p = 0; p < 2; ++p) {
                    double2 S  = uni[p][t2 * 32 + k1];
                    double2 S2 = uni[p][(t2 + 16) * 32 + k1];
                    double Ex = fma(sg, S2.x, S.x);
                    double Ey = fma(sg, S2.y, S.y);
                    double P = fma(Ex, ca, -(Ey * sa));
                    double Q = fma(Ex, sa,  (Ey * ca));
                    Ar[p] += P; Ai[p] += Q; Br[p] += Q; Bi[p] -= P;
                }
                double cn = fma(ca, wa.x, -(sa * wa.y));
                double sn = fma(sa, wa.x,  (ca * wa.y));
                ca = cn; sa = sn;
            }
            {
                const int t2 = 4 * u + 2;
#pragma unroll
                for (int p = 0; p < 2; ++p) {
                    double2 S  = uni[p][t2 * 32 + k1];
                    double2 S2 = uni[p][(t2 + 16) * 32 + k1];
                    double Ex = fma(sg, S2.x, S.x);
                    double Ey = fma(sg, S2.y, S.y);
                    double P = fma(Ex, ca, -(Ey * sa));
                    double Q = fma(Ex, sa,  (Ey * ca));
                    Ar[p] += P; Ai[p] += Q; Br[p] -= P; Bi[p] -= Q;
                }
                double cn = fma(ca, wa.x, -(sa * wa.y));
                double sn = fma(sa, wa.x,  (ca * wa.y));
                ca = cn; sa = sn;
            }
            {
                const int t2 = 4 * u + 3;
#pragma unroll
                for (int p = 0; p < 2; ++p) {
                    double2 S  = uni[p][t2 * 32 + k1];
                    double2 S2 = uni[p][(t2 + 16) * 32 + k1];
                    double Ex = fma(sg, S2.x, S.x);
                    double Ey = fma(sg, S2.y, S.y);
                    double P = fma(Ex, ca, -(Ey * sa));
                    double Q = fma(Ex, sa,  (Ey * ca));
                    Ar[p] += P; Ai[p] += Q; Br[p] -= Q; Bi[p] += P;
                }
                double cn = fma(ca, wa.x, -(sa * wa.y));
                double sn = fma(sa, wa.x,  (ca * wa.y));
                ca = cn; sa = sn;
            }
        }
    }
    const int ka = k1 + 32 * g;          // == tid
    const int kb = ka + 256;
#pragma unroll
    for (int p = 0; p < 2; ++p) {
        const size_t base = (size_t)(pair0 + p) * 512;
        double a2a = Ar[p] * Ar[p] + Ai[p] * Ai[p];
        double a2b = Br[p] * Br[p] + Bi[p] * Bi[p];
        unsigned long long bba = __double_as_longlong(a2a);
        unsigned long long bbb = __double_as_longlong(a2b);
        double keya = __longlong_as_double((bba & ~1023ULL) |
                                           (unsigned long long)(1023 - ka));
        double keyb = __longlong_as_double((bbb & ~1023ULL) |
                                           (unsigned long long)(1023 - kb));
        if (ka == 0) keya = -1.0;   // DC excluded
        keys[base + ka] = keya;
        keys[base + kb] = keyb;
        phase[base + ka] = __float2half(atan2f((float)Ai[p], (float)Ar[p]));
        phase[base + kb] = __float2half(atan2f((float)Bi[p], (float)Br[p]));
    }
}

// ---------------------------------------------------------------------------
// K2b: top-32 per pair, one WAVE per pair (unchanged from r11).
// sel = (amp, phi, k, cos(2 pi k/1024))
// ---------------------------------------------------------------------------
__global__ __launch_bounds__(256) void topk_kernel(const double* __restrict__ keys,
                                                   const __half* __restrict__ phase,
                                                   float4* __restrict__ sel) {
    const int tid  = threadIdx.x;
    const int lane = tid & 63;
    const int pair = blockIdx.x * 4 + (tid >> 6);
    const size_t base = (size_t)pair * 512;

    double kreg[8];
#pragma unroll
    for (int j = 0; j < 8; ++j) kreg[j] = keys[base + j * 64 + lane];

    double win = -2.0;
    for (int r = 0; r < 32; ++r) {
        double m01 = fmax(kreg[0], kreg[1]);
        double m23 = fmax(kreg[2], kreg[3]);
        double m45 = fmax(kreg[4], kreg[5]);
        double m67 = fmax(kreg[6], kreg[7]);
        double m = fmax(fmax(m01, m23), fmax(m45, m67));
#pragma unroll
        for (int off = 1; off < 64; off <<= 1)
            m = fmax(m, __shfl_xor(m, off));
#pragma unroll
        for (int j = 0; j < 8; ++j)
            if (kreg[j] == m) kreg[j] = -2.0;   // exact bit match (keys unique)
        if (lane == r) win = m;
    }

    if (lane < 32) {
        unsigned long long b = __double_as_longlong(win);
        int k = 1023 - (int)(b & 1023ULL);
        float ph = __half2float(phase[base + k]);
        double amp = sqrt(win);   // win = amp^2 (packed bits, rel err 2^-43)
        float aout = (float)(2.0 * amp / (1024.0 + 1e-8));
        const float C = 6.28318530717958647692f / 1024.0f;
        float tkc = __cosf((float)k * C);
        sel[(size_t)pair * 32 + lane] = make_float4(aout, ph, (float)k, tkc);
    }
}

// ---------------------------------------------------------------------------
// K3: Chebyshev reconstruction + t-periodicity (unroll 4 for chain ILP).
// ---------------------------------------------------------------------------
__global__ __launch_bounds__(256) void recon_kernel(const float4* __restrict__ sel,
                                                    const float2* __restrict__ stats,
                                                    float* __restrict__ out) {
    __shared__ float4 sel_s[32][65];
    __shared__ float2 st_s[64];
    const int bid   = blockIdx.x;
    const int chunk = bid & 15;        // 16 chunks x 64 t
    const int dt    = (bid >> 4) & 7;
    const int b     = bid >> 7;
    const int d0    = dt * 64;
    const int tid   = threadIdx.x;
#pragma unroll
    for (int it = 0; it < 8; ++it) {
        int i   = tid + it * 256;
        int j   = i & 31;
        int dls = i >> 5;
        sel_s[j][dls] = sel[((size_t)(b * D_DIM + d0 + dls)) * 32 + j];
    }
    if (tid < 64) st_s[tid] = stats[b * D_DIM + d0 + tid];
    __syncthreads();

    const int dl    = tid & 63;
    const int wvv   = tid >> 6;
    const int tbase = chunk * 64 + wvv * 16;   // < 1024

    float acc[16];
#pragma unroll
    for (int j = 0; j < 16; ++j) acc[j] = 0.0f;

    const float C = 6.28318530717958647692f / 1024.0f;
#pragma unroll 4
    for (int js = 0; js < 32; ++js) {
        float4 tr = sel_s[js][dl];       // (a, phi, k, cos(kC))
        const float a = tr.x;
        int k = (int)tr.z;
        float ck = tr.w;
        float sk = sqrtf(fmaxf(1.0f - ck * ck, 0.0f));   // k in [1,511] -> sin>0
        int mm0 = (k * tbase) & 1023;
        float ang0 = fmaf((float)mm0, C, tr.y);
        float s0, c0;
        __sincosf(ang0, &s0, &c0);
        float c1 = c0 * ck - s0 * sk;
        float K2 = ck + ck;
        acc[0] = fmaf(a, c0, acc[0]);
        acc[1] = fmaf(a, c1, acc[1]);
#pragma unroll
        for (int j = 2; j < 16; ++j) {
            float c2 = fmaf(K2, c1, -c0);
            acc[j] = fmaf(a, c2, acc[j]);
            c0 = c1; c1 = c2;
        }
    }
    const float2 st = st_s[dl];
#pragma unroll
    for (int j = 0; j < 16; ++j) {
        float o = fmaf(acc[j], st.y, st.x);
        int t = tbase + j;
        out[((size_t)b * T_OUT + t) * D_DIM + d0 + dl] = o;
        if (t < 256)
            out[((size_t)b * T_OUT + t + 1024) * D_DIM + d0 + dl] = o;
    }
}

// ---------------------------------------------------------------------------
extern "C" void kernel_launch(void* const* d_in, const int* in_sizes, int n_in,
                              void* d_out, int out_size, void* d_ws, size_t ws_size,
                              hipStream_t stream) {
    const float* x = (const float*)d_in[0];
    float* out = (float*)d_out;
    char* ws = (char*)d_ws;
    const size_t MB = 1024 * 1024;

    // layout (total ~38.1 MB; observed ws >= 39 MB):
    float*   xt    = (float*)ws;                          // 16 MB  [0,16)
    double*  keys  = (double*)(ws + 16 * MB);             // 16 MB  [16,32)
    __half*  phase = (__half*)(ws + 32 * MB);             //  4 MB  [32,36)
    double2* tw    = (double2*)(ws + 36 * MB);            // 16 KB
    float2*  stats = (float2*)(ws + 36 * MB + 65536);     // 32 KB
    float4*  sel   = (float4*)(ws + 36 * MB + 131072);    //  2 MB

    transpose_kernel<<<dim3(8, 16, 8), 256, 0, stream>>>(x, xt, tw);
    dft_kernel<<<NPAIR / 2, 256, 0, stream>>>(xt, tw, stats, keys, phase);
    topk_kernel<<<NPAIR / 4, 256, 0, stream>>>(keys, phase, sel);
    recon_kernel<<<1024, 256, 0, stream>>>(sel, stats, out);
}

// Round 14
// 83.294 us; speedup vs baseline: 1.7161x; 1.0487x over previous
//
#include <hip/hip_runtime.h>
#include <hip/hip_fp16.h>

#define T_IN 1024
#define D_DIM 512
#define T_OUT 1280
#define NPAIR 4096   // 8 * 512

// ---------------------------------------------------------------------------
// K1: transpose (b, t, d) -> (b, d, t), 64x64 LDS tiles.
// Also builds fp64 twiddles tw[m] = (cos, -sin)(2 pi m/1024), m=0..1023.
// ---------------------------------------------------------------------------
__global__ __launch_bounds__(256) void transpose_kernel(const float* __restrict__ x,
                                                        float* __restrict__ xt,
                                                        double2* __restrict__ tw) {
    __shared__ float tile[64][65];
    const int b  = blockIdx.z;
    const int t0 = blockIdx.y * 64;
    const int d0 = blockIdx.x * 64;
    const int dl = threadIdx.x & 63;
    const int r0 = threadIdx.x >> 6;   // 0..3

    if (blockIdx.x < 4 && blockIdx.y == 0 && blockIdx.z == 0) {
        int m = blockIdx.x * 256 + threadIdx.x;
        double th = (6.283185307179586476925286766559 / 1024.0) * (double)m;
        tw[m] = make_double2(cos(th), -sin(th));
    }

#pragma unroll
    for (int i = 0; i < 16; ++i) {
        int tl = r0 * 16 + i;
        tile[tl][dl] = x[((size_t)b * T_IN + (t0 + tl)) * D_DIM + d0 + dl];
    }
    __syncthreads();
#pragma unroll
    for (int i = 0; i < 16; ++i) {
        int dl2 = r0 * 16 + i;
        xt[((size_t)b * D_DIM + (d0 + dl2)) * T_IN + t0 + dl] = tile[dl][dl2];
    }
}

// ---------------------------------------------------------------------------
// eighth-table twiddle lookup: e^{-2 pi i m/1024}, m in [0, 1024)
// ---------------------------------------------------------------------------
__device__ __forceinline__ double2 TW8(const double2* __restrict__ E, int m) {
    int r = m & 255;
    int q = (m >> 8) & 3;
    double c, s;
    if (r <= 128) { double2 t = E[r];       c = t.x; s = t.y; }
    else          { double2 t = E[256 - r]; c = t.y; s = t.x; }
    double C, S;
    switch (q) {
        case 0:  C = c;  S = s;  break;
        case 1:  C = -s; S = c;  break;
        case 2:  C = -c; S = -s; break;
        default: C = s;  S = -c; break;
    }
    return make_double2(C, -S);
}

// ---------------------------------------------------------------------------
// K2 (r11-proven): per (b,d): stats -> standardize/clip -> even/odd butterfly
// -> 1024-pt real DFT (32x32 Cooley-Tukey, fp64, folded stage 2)
// -> fp64 amp^2 sort-keys + half phase.
// ---------------------------------------------------------------------------
__global__ __launch_bounds__(256) void dft_kernel(const float* __restrict__ xt,
                                                  const double2* __restrict__ twg,
                                                  float2* __restrict__ stats,
                                                  double* __restrict__ keys,
                                                  __half* __restrict__ phase) {
    __shared__ double2 uni[1024];       // phase A: xs (1024 dbl); phase B: S[32][32]
    __shared__ double2 tw_s[130];       // eighth table E[0..128]
    __shared__ double  red_s[16];
    double* xs_s = (double*)uni;

    const int tid  = threadIdx.x;
    const int pair = blockIdx.x;

    const float4 v = reinterpret_cast<const float4*>(xt + (size_t)pair * T_IN)[tid];

    if (tid < 130) {
        double2 t = twg[tid];                 // (cos, -sin)
        tw_s[tid] = make_double2(t.x, -t.y);  // store (cos, +sin)
    }

    // --- stats (fp64, deterministic tree reduce; final sum redundant per-thread) ---
    double sum = (double)v.x + (double)v.y + (double)v.z + (double)v.w;
    double sq  = (double)v.x * v.x + (double)v.y * v.y +
                 (double)v.z * v.z + (double)v.w * v.w;
#pragma unroll
    for (int off = 32; off; off >>= 1) {
        sum += __shfl_down(sum, off);
        sq  += __shfl_down(sq, off);
    }
    const int wv = tid >> 6;
    if ((tid & 63) == 0) { red_s[wv] = sum; red_s[8 + wv] = sq; }
    __syncthreads();
    double mean, stdp;
    {
        double s = red_s[0] + red_s[1] + red_s[2] + red_s[3];
        double q = red_s[8] + red_s[9] + red_s[10] + red_s[11];
        mean = s * (1.0 / 1024.0);
        double var = (q - 1024.0 * mean * mean) * (1.0 / 1023.0);
        var = var > 0.0 ? var : 0.0;
        stdp = sqrt(var) + 1e-8;   // reference: std + 1e-8
        if (tid == 0) stats[pair] = make_float2((float)mean, (float)stdp);
    }
    const double inv = 1.0 / stdp;
    {
        double z0 = ((double)v.x - mean) * inv;
        double z1 = ((double)v.y - mean) * inv;
        double z2 = ((double)v.z - mean) * inv;
        double z3 = ((double)v.w - mean) * inv;
        z0 = fmin(2.0, fmax(-2.0, z0)) + 1e-9;
        z1 = fmin(2.0, fmax(-2.0, z1)) + 1e-9;
        z2 = fmin(2.0, fmax(-2.0, z2)) + 1e-9;
        z3 = fmin(2.0, fmax(-2.0, z3)) + 1e-9;
        xs_s[tid * 4 + 0] = z0;
        xs_s[tid * 4 + 1] = z1;
        xs_s[tid * 4 + 2] = z2;
        xs_s[tid * 4 + 3] = z3;
    }
    __syncthreads();

    // --- in-place even/odd butterfly over t1 (pairs t1 <-> 32-t1, t1=1..15) ---
    {
        int idx = tid;
#pragma unroll
        for (int rr = 0; rr < 2; ++rr) {
            if (idx < 480) {
                int t1p = 1 + (idx >> 5);
                int t2c = idx & 31;
                int ia = t1p * 32 + t2c;
                int ib = (32 - t1p) * 32 + t2c;
                double a = xs_s[ia], b = xs_s[ib];
                xs_s[ia] = a + b;
                xs_s[ib] = a - b;
            }
            idx += 256;
        }
    }
    __syncthreads();

    const int k1 = tid & 31;
    const int g  = tid >> 5;   // 0..7

    // --- stage 1 (into registers) ---
    double2 R0, R1, R2, R3;
    {
        const double2 w = TW8(tw_s, k1 * 32);   // e^{-2 pi i k1/32}
        const double sgn16 = (k1 & 1) ? -1.0 : 1.0;

        double ar0 = xs_s[g]      + sgn16 * xs_s[512 + g];
        double ar1 = xs_s[g + 8]  + sgn16 * xs_s[512 + g + 8];
        double ar2 = xs_s[g + 16] + sgn16 * xs_s[512 + g + 16];
        double ar3 = xs_s[g + 24] + sgn16 * xs_s[512 + g + 24];
        double ai0 = 0, ai1 = 0, ai2 = 0, ai3 = 0;

        double c = w.x, s = w.y;   // t1 = 1
#pragma unroll 5
        for (int t1 = 1; t1 <= 15; ++t1) {
            const double* eb = &xs_s[t1 * 32];
            const double* ob = &xs_s[(32 - t1) * 32];
            ar0 = fma(eb[g], c, ar0);      ai0 = fma(ob[g], s, ai0);
            ar1 = fma(eb[g + 8], c, ar1);  ai1 = fma(ob[g + 8], s, ai1);
            ar2 = fma(eb[g + 16], c, ar2); ai2 = fma(ob[g + 16], s, ai2);
            ar3 = fma(eb[g + 24], c, ar3); ai3 = fma(ob[g + 24], s, ai3);
            double cn = c * w.x - s * w.y;
            double sn = s * w.x + c * w.y;
            c = cn; s = sn;
        }
        {
            double2 tm = TW8(tw_s, g * k1);
            R0 = make_double2(ar0 * tm.x - ai0 * tm.y, ar0 * tm.y + ai0 * tm.x);
        }
        {
            double2 tm = TW8(tw_s, (g + 8) * k1);
            R1 = make_double2(ar1 * tm.x - ai1 * tm.y, ar1 * tm.y + ai1 * tm.x);
        }
        {
            double2 tm = TW8(tw_s, (g + 16) * k1);
            R2 = make_double2(ar2 * tm.x - ai2 * tm.y, ar2 * tm.y + ai2 * tm.x);
        }
        {
            double2 tm = TW8(tw_s, (g + 24) * k1);
            R3 = make_double2(ar3 * tm.x - ai3 * tm.y, ar3 * tm.y + ai3 * tm.x);
        }
    }
    __syncthreads();   // xs reads done -> overwrite union with S

    uni[g * 32 + k1]        = R0;
    uni[(g + 8) * 32 + k1]  = R1;
    uni[(g + 16) * 32 + k1] = R2;
    uni[(g + 24) * 32 + k1] = R3;
    __syncthreads();

    // --- stage 2 (folded): E[t2] = S[t2] + (-1)^g S[t2+16], bins g and g+8
    //     via W32^{t2(g+8)} = W32^{t2 g} * (-i)^{t2}.
    double Ar = 0, Ai = 0, Br = 0, Bi = 0;
    {
        const double2 wa = TW8(tw_s, 32 * g);   // e^{-2 pi i g/32}
        const double sg = (g & 1) ? -1.0 : 1.0;
        double ca = 1.0, sa = 0.0;
#pragma unroll
        for (int u = 0; u < 4; ++u) {
            {
                const int t2 = 4 * u + 0;
                double2 S  = uni[t2 * 32 + k1];
                double2 S2 = uni[(t2 + 16) * 32 + k1];
                double Ex = fma(sg, S2.x, S.x);
                double Ey = fma(sg, S2.y, S.y);
                double P = fma(Ex, ca, -(Ey * sa));
                double Q = fma(Ex, sa,  (Ey * ca));
                Ar += P; Ai += Q; Br += P; Bi += Q;
                double cn = fma(ca, wa.x, -(sa * wa.y));
                double sn = fma(sa, wa.x,  (ca * wa.y));
                ca = cn; sa = sn;
            }
            {
                const int t2 = 4 * u + 1;
                double2 S  = uni[t2 * 32 + k1];
                double2 S2 = uni[(t2 + 16) * 32 + k1];
                double Ex = fma(sg, S2.x, S.x);
                double Ey = fma(sg, S2.y, S.y);
                double P = fma(Ex, ca, -(Ey * sa));
                double Q = fma(Ex, sa,  (Ey * ca));
                Ar += P; Ai += Q; Br += Q; Bi -= P;
                double cn = fma(ca, wa.x, -(sa * wa.y));
                double sn = fma(sa, wa.x,  (ca * wa.y));
                ca = cn; sa = sn;
            }
            {
                const int t2 = 4 * u + 2;
                double2 S  = uni[t2 * 32 + k1];
                double2 S2 = uni[(t2 + 16) * 32 + k1];
                double Ex = fma(sg, S2.x, S.x);
                double Ey = fma(sg, S2.y, S.y);
                double P = fma(Ex, ca, -(Ey * sa));
                double Q = fma(Ex, sa,  (Ey * ca));
                Ar += P; Ai += Q; Br -= P; Bi -= Q;
                double cn = fma(ca, wa.x, -(sa * wa.y));
                double sn = fma(sa, wa.x,  (ca * wa.y));
                ca = cn; sa = sn;
            }
            {
                const int t2 = 4 * u + 3;
                double2 S  = uni[t2 * 32 + k1];
                double2 S2 = uni[(t2 + 16) * 32 + k1];
                double Ex = fma(sg, S2.x, S.x);
                double Ey = fma(sg, S2.y, S.y);
                double P = fma(Ex, ca, -(Ey * sa));
                double Q = fma(Ex, sa,  (Ey * ca));
                Ar += P; Ai += Q; Br -= Q; Bi += P;
                double cn = fma(ca, wa.x, -(sa * wa.y));
                double sn = fma(sa, wa.x,  (ca * wa.y));
                ca = cn; sa = sn;
            }
        }
    }
    const int ka = k1 + 32 * g;          // == tid
    const int kb = ka + 256;
    const size_t base = (size_t)pair * 512;
    {
        double a2a = Ar * Ar + Ai * Ai;
        double a2b = Br * Br + Bi * Bi;
        unsigned long long bba = __double_as_longlong(a2a);
        unsigned long long bbb = __double_as_longlong(a2b);
        double keya = __longlong_as_double((bba & ~1023ULL) |
                                           (unsigned long long)(1023 - ka));
        double keyb = __longlong_as_double((bbb & ~1023ULL) |
                                           (unsigned long long)(1023 - kb));
        if (ka == 0) keya = -1.0;   // DC excluded
        keys[base + ka] = keya;
        keys[base + kb] = keyb;
        phase[base + ka] = __float2half(atan2f((float)Ai, (float)Ar));
        phase[base + kb] = __float2half(atan2f((float)Bi, (float)Br));
    }
}

// ---------------------------------------------------------------------------
// K2b v2: top-32 per pair, one WAVE per pair — NO shfl chains.
// Bit-descend (MSB-first) on uint64-mapped keys finds the exact 32nd-largest
// key via ballot counts (v_cmp -> vcc -> scalar popcount). Winners = keys >=
// threshold (exactly 32, keys unique). Slots via ballot prefix-popcount —
// output order arbitrary (recon sums over all 32).
// sel = (amp, phi, k, cos(2 pi k/1024))
// ---------------------------------------------------------------------------
__global__ __launch_bounds__(256) void topk_kernel(const double* __restrict__ keys,
                                                   const __half* __restrict__ phase,
                                                   float4* __restrict__ sel) {
    const int tid  = threadIdx.x;
    const int lane = tid & 63;
    const int pair = blockIdx.x * 4 + (tid >> 6);
    const size_t base = (size_t)pair * 512;

    // monotone map double -> uint64 (handles the -1.0 DC sentinel)
    unsigned long long kb[8];
#pragma unroll
    for (int j = 0; j < 8; ++j) {
        unsigned long long u =
            (unsigned long long)__double_as_longlong(keys[base + j * 64 + lane]);
        u ^= (u >> 63) ? 0xFFFFFFFFFFFFFFFFULL : 0x8000000000000000ULL;
        kb[j] = u;
    }

    // MSB-first bit-descend: final prefix == exact 32nd-largest key bits
    unsigned long long prefix = 0;
    for (int bit = 63; bit >= 0; --bit) {
        unsigned long long trial = prefix | (1ULL << bit);
        int cnt = 0;
#pragma unroll
        for (int j = 0; j < 8; ++j)
            cnt += __popcll(__ballot(kb[j] >= trial));
        if (cnt >= 32) prefix = trial;
    }

    // winners (exactly 32): compact via ballot prefix-popcount, decode, write
    const unsigned long long lmask = (lane == 0) ? 0ULL
                                   : (0xFFFFFFFFFFFFFFFFULL >> (64 - lane));
    int slot = 0;
#pragma unroll
    for (int j = 0; j < 8; ++j) {
        unsigned long long m = __ballot(kb[j] >= prefix);
        if (kb[j] >= prefix) {
            int my = slot + __popcll(m & lmask);
            unsigned long long u = kb[j] ^ 0x8000000000000000ULL;  // winners > 0
            double key = __longlong_as_double((long long)u);
            int k = 1023 - (int)(u & 1023ULL);
            float ph = __half2float(phase[base + k]);
            double amp = sqrt(key);   // key = amp^2 (packed bits, rel err 2^-43)
            float aout = (float)(2.0 * amp / (1024.0 + 1e-8));
            const float C = 6.28318530717958647692f / 1024.0f;
            float tkc = __cosf((float)k * C);
            sel[(size_t)pair * 32 + my] = make_float4(aout, ph, (float)k, tkc);
        }
        slot += __popcll(m);
    }
}

// ---------------------------------------------------------------------------
// K3: Chebyshev reconstruction + t-periodicity (r11-proven).
// cos(ang0 + n*kC) via c_{n+1} = 2cos(kC)*c_n - c_{n-1}: 2 fma/term.
// out[t+1024] = out[t] for t<256 (angle periodic mod 2pi, exact).
// ---------------------------------------------------------------------------
__global__ __launch_bounds__(256) void recon_kernel(const float4* __restrict__ sel,
                                                    const float2* __restrict__ stats,
                                                    float* __restrict__ out) {
    __shared__ float4 sel_s[32][65];
    __shared__ float2 st_s[64];
    const int bid   = blockIdx.x;
    const int chunk = bid & 15;        // 16 chunks x 64 t
    const int dt    = (bid >> 4) & 7;
    const int b     = bid >> 7;
    const int d0    = dt * 64;
    const int tid   = threadIdx.x;
#pragma unroll
    for (int it = 0; it < 8; ++it) {
        int i   = tid + it * 256;
        int j   = i & 31;
        int dls = i >> 5;
        sel_s[j][dls] = sel[((size_t)(b * D_DIM + d0 + dls)) * 32 + j];
    }
    if (tid < 64) st_s[tid] = stats[b * D_DIM + d0 + tid];
    __syncthreads();

    const int dl    = tid & 63;
    const int wvv   = tid >> 6;
    const int tbase = chunk * 64 + wvv * 16;   // < 1024

    float acc[16];
#pragma unroll
    for (int j = 0; j < 16; ++j) acc[j] = 0.0f;

    const float C = 6.28318530717958647692f / 1024.0f;
#pragma unroll 2
    for (int js = 0; js < 32; ++js) {
        float4 tr = sel_s[js][dl];       // (a, phi, k, cos(kC))
        const float a = tr.x;
        int k = (int)tr.z;
        float ck = tr.w;
        float sk = sqrtf(fmaxf(1.0f - ck * ck, 0.0f));   // k in [1,511] -> sin>0
        int mm0 = (k * tbase) & 1023;
        float ang0 = fmaf((float)mm0, C, tr.y);
        float s0, c0;
        __sincosf(ang0, &s0, &c0);
        float c1 = c0 * ck - s0 * sk;
        float K2 = ck + ck;
        acc[0] = fmaf(a, c0, acc[0]);
        acc[1] = fmaf(a, c1, acc[1]);
#pragma unroll
        for (int j = 2; j < 16; ++j) {
            float c2 = fmaf(K2, c1, -c0);
            acc[j] = fmaf(a, c2, acc[j]);
            c0 = c1; c1 = c2;
        }
    }
    const float2 st = st_s[dl];
#pragma unroll
    for (int j = 0; j < 16; ++j) {
        float o = fmaf(acc[j], st.y, st.x);
        int t = tbase + j;
        out[((size_t)b * T_OUT + t) * D_DIM + d0 + dl] = o;
        if (t < 256)
            out[((size_t)b * T_OUT + t + 1024) * D_DIM + d0 + dl] = o;
    }
}

// ---------------------------------------------------------------------------
extern "C" void kernel_launch(void* const* d_in, const int* in_sizes, int n_in,
                              void* d_out, int out_size, void* d_ws, size_t ws_size,
                              hipStream_t stream) {
    const float* x = (const float*)d_in[0];
    float* out = (float*)d_out;
    char* ws = (char*)d_ws;
    const size_t MB = 1024 * 1024;

    // layout (total ~38.1 MB; observed ws >= 39 MB):
    float*   xt    = (float*)ws;                          // 16 MB  [0,16)
    double*  keys  = (double*)(ws + 16 * MB);             // 16 MB  [16,32)
    __half*  phase = (__half*)(ws + 32 * MB);             //  4 MB  [32,36)
    double2* tw    = (double2*)(ws + 36 * MB);            // 16 KB
    float2*  stats = (float2*)(ws + 36 * MB + 65536);     // 32 KB
    float4*  sel   = (float4*)(ws + 36 * MB + 131072);    //  2 MB

    transpose_kernel<<<dim3(8, 16, 8), 256, 0, stream>>>(x, xt, tw);
    dft_kernel<<<NPAIR, 256, 0, stream>>>(xt, tw, stats, keys, phase);
    topk_kernel<<<NPAIR / 4, 256, 0, stream>>>(keys, phase, sel);
    recon_kernel<<<1024, 256, 0, stream>>>(sel, stats, out);
}

// Round 15
// 77.830 us; speedup vs baseline: 1.8366x; 1.0702x over previous
//
#include <hip/hip_runtime.h>

#define T_IN 1024
#define D_DIM 512
#define T_OUT 1280
#define NPAIR 4096   // 8 * 512

// ---------------------------------------------------------------------------
// K1: transpose (b, t, d) -> (b, d, t), 64x64 LDS tiles.
// Also builds fp64 twiddles tw[m] = (cos, -sin)(2 pi m/1024), m=0..1023.
// ---------------------------------------------------------------------------
__global__ __launch_bounds__(256) void transpose_kernel(const float* __restrict__ x,
                                                        float* __restrict__ xt,
                                                        double2* __restrict__ tw) {
    __shared__ float tile[64][65];
    const int b  = blockIdx.z;
    const int t0 = blockIdx.y * 64;
    const int d0 = blockIdx.x * 64;
    const int dl = threadIdx.x & 63;
    const int r0 = threadIdx.x >> 6;   // 0..3

    if (blockIdx.x < 4 && blockIdx.y == 0 && blockIdx.z == 0) {
        int m = blockIdx.x * 256 + threadIdx.x;
        double th = (6.283185307179586476925286766559 / 1024.0) * (double)m;
        tw[m] = make_double2(cos(th), -sin(th));
    }

#pragma unroll
    for (int i = 0; i < 16; ++i) {
        int tl = r0 * 16 + i;
        tile[tl][dl] = x[((size_t)b * T_IN + (t0 + tl)) * D_DIM + d0 + dl];
    }
    __syncthreads();
#pragma unroll
    for (int i = 0; i < 16; ++i) {
        int dl2 = r0 * 16 + i;
        xt[((size_t)b * D_DIM + (d0 + dl2)) * T_IN + t0 + dl] = tile[dl][dl2];
    }
}

// ---------------------------------------------------------------------------
// eighth-table twiddle lookup: e^{-2 pi i m/1024}, m in [0, 1024)
// ---------------------------------------------------------------------------
__device__ __forceinline__ double2 TW8(const double2* __restrict__ E, int m) {
    int r = m & 255;
    int q = (m >> 8) & 3;
    double c, s;
    if (r <= 128) { double2 t = E[r];       c = t.x; s = t.y; }
    else          { double2 t = E[256 - r]; c = t.y; s = t.x; }
    double C, S;
    switch (q) {
        case 0:  C = c;  S = s;  break;
        case 1:  C = -s; S = c;  break;
        case 2:  C = -c; S = -s; break;
        default: C = s;  S = -c; break;
    }
    return make_double2(C, -S);
}

// ---------------------------------------------------------------------------
// K2 (fused, barrier-light): per (b,d): stats -> standardize/clip -> even/odd
// butterfly -> 1024-pt real DFT (fp64, folded stage 2) -> hierarchical top-32:
//   phase A: per-wave bit-descend over its 128 keys (ballots only, NO barriers)
//            -> wave top-32 compacted to LDS cand[128]
//   one barrier
//   phase B: wave 0 bit-descend over 128 candidates -> exact global top-32,
//            decode + atan2f/sqrt/cos on 32 lanes, write sel.
// sel = (amp, phi, k, cos(2 pi k/1024))
// ---------------------------------------------------------------------------
__global__ __launch_bounds__(256) void dft_kernel(const float* __restrict__ xt,
                                                  const double2* __restrict__ twg,
                                                  float2* __restrict__ stats,
                                                  float4* __restrict__ sel) {
    __shared__ double2 uni[1024];       // A: xs (1024 dbl); B: S[32][32];
                                        // C: spec float2[512] (bytes 0..4K) +
                                        //    cand double[128] (bytes 8K..9K)
    __shared__ double2 tw_s[130];       // eighth table E[0..128]
    __shared__ double  red_s[16];
    double* xs_s = (double*)uni;

    const int tid  = threadIdx.x;
    const int pair = blockIdx.x;

    const float4 v = reinterpret_cast<const float4*>(xt + (size_t)pair * T_IN)[tid];

    if (tid < 130) {
        double2 t = twg[tid];                 // (cos, -sin)
        tw_s[tid] = make_double2(t.x, -t.y);  // store (cos, +sin)
    }

    // --- stats (fp64, deterministic tree reduce; final sum redundant per-thread) ---
    double sum = (double)v.x + (double)v.y + (double)v.z + (double)v.w;
    double sq  = (double)v.x * v.x + (double)v.y * v.y +
                 (double)v.z * v.z + (double)v.w * v.w;
#pragma unroll
    for (int off = 32; off; off >>= 1) {
        sum += __shfl_down(sum, off);
        sq  += __shfl_down(sq, off);
    }
    const int wv   = tid >> 6;
    const int lane = tid & 63;
    if (lane == 0) { red_s[wv] = sum; red_s[8 + wv] = sq; }
    __syncthreads();
    double mean, stdp;
    {
        double s = red_s[0] + red_s[1] + red_s[2] + red_s[3];
        double q = red_s[8] + red_s[9] + red_s[10] + red_s[11];
        mean = s * (1.0 / 1024.0);
        double var = (q - 1024.0 * mean * mean) * (1.0 / 1023.0);
        var = var > 0.0 ? var : 0.0;
        stdp = sqrt(var) + 1e-8;   // reference: std + 1e-8
        if (tid == 0) stats[pair] = make_float2((float)mean, (float)stdp);
    }
    const double inv = 1.0 / stdp;
    {
        double z0 = ((double)v.x - mean) * inv;
        double z1 = ((double)v.y - mean) * inv;
        double z2 = ((double)v.z - mean) * inv;
        double z3 = ((double)v.w - mean) * inv;
        z0 = fmin(2.0, fmax(-2.0, z0)) + 1e-9;
        z1 = fmin(2.0, fmax(-2.0, z1)) + 1e-9;
        z2 = fmin(2.0, fmax(-2.0, z2)) + 1e-9;
        z3 = fmin(2.0, fmax(-2.0, z3)) + 1e-9;
        xs_s[tid * 4 + 0] = z0;
        xs_s[tid * 4 + 1] = z1;
        xs_s[tid * 4 + 2] = z2;
        xs_s[tid * 4 + 3] = z3;
    }
    __syncthreads();

    // --- in-place even/odd butterfly over t1 (pairs t1 <-> 32-t1, t1=1..15) ---
    {
        int idx = tid;
#pragma unroll
        for (int rr = 0; rr < 2; ++rr) {
            if (idx < 480) {
                int t1p = 1 + (idx >> 5);
                int t2c = idx & 31;
                int ia = t1p * 32 + t2c;
                int ib = (32 - t1p) * 32 + t2c;
                double a = xs_s[ia], b = xs_s[ib];
                xs_s[ia] = a + b;
                xs_s[ib] = a - b;
            }
            idx += 256;
        }
    }
    __syncthreads();

    const int k1 = tid & 31;
    const int g  = tid >> 5;   // 0..7

    // --- stage 1 (into registers) ---
    double2 R0, R1, R2, R3;
    {
        const double2 w = TW8(tw_s, k1 * 32);   // e^{-2 pi i k1/32}
        const double sgn16 = (k1 & 1) ? -1.0 : 1.0;

        double ar0 = xs_s[g]      + sgn16 * xs_s[512 + g];
        double ar1 = xs_s[g + 8]  + sgn16 * xs_s[512 + g + 8];
        double ar2 = xs_s[g + 16] + sgn16 * xs_s[512 + g + 16];
        double ar3 = xs_s[g + 24] + sgn16 * xs_s[512 + g + 24];
        double ai0 = 0, ai1 = 0, ai2 = 0, ai3 = 0;

        double c = w.x, s = w.y;   // t1 = 1
#pragma unroll 5
        for (int t1 = 1; t1 <= 15; ++t1) {
            const double* eb = &xs_s[t1 * 32];
            const double* ob = &xs_s[(32 - t1) * 32];
            ar0 = fma(eb[g], c, ar0);      ai0 = fma(ob[g], s, ai0);
            ar1 = fma(eb[g + 8], c, ar1);  ai1 = fma(ob[g + 8], s, ai1);
            ar2 = fma(eb[g + 16], c, ar2); ai2 = fma(ob[g + 16], s, ai2);
            ar3 = fma(eb[g + 24], c, ar3); ai3 = fma(ob[g + 24], s, ai3);
            double cn = c * w.x - s * w.y;
            double sn = s * w.x + c * w.y;
            c = cn; s = sn;
        }
        {
            double2 tm = TW8(tw_s, g * k1);
            R0 = make_double2(ar0 * tm.x - ai0 * tm.y, ar0 * tm.y + ai0 * tm.x);
        }
        {
            double2 tm = TW8(tw_s, (g + 8) * k1);
            R1 = make_double2(ar1 * tm.x - ai1 * tm.y, ar1 * tm.y + ai1 * tm.x);
        }
        {
            double2 tm = TW8(tw_s, (g + 16) * k1);
            R2 = make_double2(ar2 * tm.x - ai2 * tm.y, ar2 * tm.y + ai2 * tm.x);
        }
        {
            double2 tm = TW8(tw_s, (g + 24) * k1);
            R3 = make_double2(ar3 * tm.x - ai3 * tm.y, ar3 * tm.y + ai3 * tm.x);
        }
    }
    __syncthreads();   // xs reads done -> overwrite union with S

    uni[g * 32 + k1]        = R0;
    uni[(g + 8) * 32 + k1]  = R1;
    uni[(g + 16) * 32 + k1] = R2;
    uni[(g + 24) * 32 + k1] = R3;
    __syncthreads();

    // --- stage 2 (folded): E[t2] = S[t2] + (-1)^g S[t2+16], bins g and g+8
    //     via W32^{t2(g+8)} = W32^{t2 g} * (-i)^{t2}.
    double Ar = 0, Ai = 0, Br = 0, Bi = 0;
    {
        const double2 wa = TW8(tw_s, 32 * g);   // e^{-2 pi i g/32}
        const double sg = (g & 1) ? -1.0 : 1.0;
        double ca = 1.0, sa = 0.0;
#pragma unroll
        for (int u = 0; u < 4; ++u) {
            {
                const int t2 = 4 * u + 0;
                double2 S  = uni[t2 * 32 + k1];
                double2 S2 = uni[(t2 + 16) * 32 + k1];
                double Ex = fma(sg, S2.x, S.x);
                double Ey = fma(sg, S2.y, S.y);
                double P = fma(Ex, ca, -(Ey * sa));
                double Q = fma(Ex, sa,  (Ey * ca));
                Ar += P; Ai += Q; Br += P; Bi += Q;
                double cn = fma(ca, wa.x, -(sa * wa.y));
                double sn = fma(sa, wa.x,  (ca * wa.y));
                ca = cn; sa = sn;
            }
            {
                const int t2 = 4 * u + 1;
                double2 S  = uni[t2 * 32 + k1];
                double2 S2 = uni[(t2 + 16) * 32 + k1];
                double Ex = fma(sg, S2.x, S.x);
                double Ey = fma(sg, S2.y, S.y);
                double P = fma(Ex, ca, -(Ey * sa));
                double Q = fma(Ex, sa,  (Ey * ca));
                Ar += P; Ai += Q; Br += Q; Bi -= P;
                double cn = fma(ca, wa.x, -(sa * wa.y));
                double sn = fma(sa, wa.x,  (ca * wa.y));
                ca = cn; sa = sn;
            }
            {
                const int t2 = 4 * u + 2;
                double2 S  = uni[t2 * 32 + k1];
                double2 S2 = uni[(t2 + 16) * 32 + k1];
                double Ex = fma(sg, S2.x, S.x);
                double Ey = fma(sg, S2.y, S.y);
                double P = fma(Ex, ca, -(Ey * sa));
                double Q = fma(Ex, sa,  (Ey * ca));
                Ar += P; Ai += Q; Br -= P; Bi -= Q;
                double cn = fma(ca, wa.x, -(sa * wa.y));
                double sn = fma(sa, wa.x,  (ca * wa.y));
                ca = cn; sa = sn;
            }
            {
                const int t2 = 4 * u + 3;
                double2 S  = uni[t2 * 32 + k1];
                double2 S2 = uni[(t2 + 16) * 32 + k1];
                double Ex = fma(sg, S2.x, S.x);
                double Ey = fma(sg, S2.y, S.y);
                double P = fma(Ex, ca, -(Ey * sa));
                double Q = fma(Ex, sa,  (Ey * ca));
                Ar += P; Ai += Q; Br -= Q; Bi += P;
                double cn = fma(ca, wa.x, -(sa * wa.y));
                double sn = fma(sa, wa.x,  (ca * wa.y));
                ca = cn; sa = sn;
            }
        }
    }
    const int ka = k1 + 32 * g;          // == tid
    const int kb = ka + 256;

    // amp^2 keys, (1023-k) packed in low 10 mantissa bits (lax.top_k tiebreak),
    // mapped monotonically to uint64.
    unsigned long long uA, uB;
    {
        double a2a = Ar * Ar + Ai * Ai;
        double a2b = Br * Br + Bi * Bi;
        unsigned long long bba = __double_as_longlong(a2a);
        unsigned long long bbb = __double_as_longlong(a2b);
        double keya = __longlong_as_double((bba & ~1023ULL) |
                                           (unsigned long long)(1023 - ka));
        double keyb = __longlong_as_double((bbb & ~1023ULL) |
                                           (unsigned long long)(1023 - kb));
        if (ka == 0) keya = -1.0;   // DC excluded
        unsigned long long a = (unsigned long long)__double_as_longlong(keya);
        unsigned long long b = (unsigned long long)__double_as_longlong(keyb);
        uA = a ^ ((a >> 63) ? 0xFFFFFFFFFFFFFFFFULL : 0x8000000000000000ULL);
        uB = b ^ ((b >> 63) ? 0xFFFFFFFFFFFFFFFFULL : 0x8000000000000000ULL);
    }

    // park spec (float2) in LDS bytes [0,4K); cand (double[128]) at bytes [8K,9K)
    __syncthreads();   // stage-2 LDS reads complete
    float2* spec_f = (float2*)uni;
    double* cand   = (double*)(uni + 512);
    spec_f[ka] = make_float2((float)Ar, (float)Ai);
    spec_f[kb] = make_float2((float)Br, (float)Bi);

    // --- phase A: per-wave top-32 of its 128 keys (ballot bit-descend) ---
    const unsigned long long lt = lane ? (0xFFFFFFFFFFFFFFFFULL >> (64 - lane))
                                       : 0ULL;
    {
        unsigned long long pref = 0;
        for (int bit = 63; bit >= 0; --bit) {
            unsigned long long trial = pref | (1ULL << bit);
            int cnt = __popcll(__ballot(uA >= trial)) +
                      __popcll(__ballot(uB >= trial));
            if (cnt >= 32) pref = trial;
        }
        unsigned long long mA = __ballot(uA >= pref);
        unsigned long long mB = __ballot(uB >= pref);
        const int bs = wv * 32;
        if (uA >= pref)
            cand[bs + __popcll(mA & lt)] =
                __longlong_as_double((long long)uA);
        if (uB >= pref)
            cand[bs + __popcll(mA) + __popcll(mB & lt)] =
                __longlong_as_double((long long)uB);
    }
    __syncthreads();

    // --- phase B: wave 0 selects global top-32 from 128 candidates ---
    if (tid < 64) {
        unsigned long long c0 =
            (unsigned long long)__double_as_longlong(cand[tid]);
        unsigned long long c1 =
            (unsigned long long)__double_as_longlong(cand[tid + 64]);
        unsigned long long pref = 0;
        for (int bit = 63; bit >= 0; --bit) {
            unsigned long long trial = pref | (1ULL << bit);
            int cnt = __popcll(__ballot(c0 >= trial)) +
                      __popcll(__ballot(c1 >= trial));
            if (cnt >= 32) pref = trial;
        }
        unsigned long long m0 = __ballot(c0 >= pref);
        unsigned long long m1 = __ballot(c1 >= pref);
        const float C = 6.28318530717958647692f / 1024.0f;
        const size_t sb = (size_t)pair * 32;
        if (c0 >= pref) {
            int slot = __popcll(m0 & lt);
            int k = 1023 - (int)(c0 & 1023ULL);
            float2 sp = spec_f[k];
            float ph = atan2f(sp.y, sp.x);
            double key = __longlong_as_double(
                (long long)(c0 ^ 0x8000000000000000ULL));
            double amp = sqrt(key);
            float aout = (float)(2.0 * amp / (1024.0 + 1e-8));
            float tkc = __cosf((float)k * C);
            sel[sb + slot] = make_float4(aout, ph, (float)k, tkc);
        }
        if (c1 >= pref) {
            int slot = __popcll(m0) + __popcll(m1 & lt);
            int k = 1023 - (int)(c1 & 1023ULL);
            float2 sp = spec_f[k];
            float ph = atan2f(sp.y, sp.x);
            double key = __longlong_as_double(
                (long long)(c1 ^ 0x8000000000000000ULL));
            double amp = sqrt(key);
            float aout = (float)(2.0 * amp / (1024.0 + 1e-8));
            float tkc = __cosf((float)k * C);
            sel[sb + slot] = make_float4(aout, ph, (float)k, tkc);
        }
    }
}

// ---------------------------------------------------------------------------
// K3: Chebyshev reconstruction + t-periodicity (r11-proven).
// cos(ang0 + n*kC) via c_{n+1} = 2cos(kC)*c_n - c_{n-1}: 2 fma/term.
// out[t+1024] = out[t] for t<256 (angle periodic mod 2pi, exact).
// ---------------------------------------------------------------------------
__global__ __launch_bounds__(256) void recon_kernel(const float4* __restrict__ sel,
                                                    const float2* __restrict__ stats,
                                                    float* __restrict__ out) {
    __shared__ float4 sel_s[32][65];
    __shared__ float2 st_s[64];
    const int bid   = blockIdx.x;
    const int chunk = bid & 15;        // 16 chunks x 64 t
    const int dt    = (bid >> 4) & 7;
    const int b     = bid >> 7;
    const int d0    = dt * 64;
    const int tid   = threadIdx.x;
#pragma unroll
    for (int it = 0; it < 8; ++it) {
        int i   = tid + it * 256;
        int j   = i & 31;
        int dls = i >> 5;
        sel_s[j][dls] = sel[((size_t)(b * D_DIM + d0 + dls)) * 32 + j];
    }
    if (tid < 64) st_s[tid] = stats[b * D_DIM + d0 + tid];
    __syncthreads();

    const int dl    = tid & 63;
    const int wvv   = tid >> 6;
    const int tbase = chunk * 64 + wvv * 16;   // < 1024

    float acc[16];
#pragma unroll
    for (int j = 0; j < 16; ++j) acc[j] = 0.0f;

    const float C = 6.28318530717958647692f / 1024.0f;
#pragma unroll 2
    for (int js = 0; js < 32; ++js) {
        float4 tr = sel_s[js][dl];       // (a, phi, k, cos(kC))
        const float a = tr.x;
        int k = (int)tr.z;
        float ck = tr.w;
        float sk = sqrtf(fmaxf(1.0f - ck * ck, 0.0f));   // k in [1,511] -> sin>0
        int mm0 = (k * tbase) & 1023;
        float ang0 = fmaf((float)mm0, C, tr.y);
        float s0, c0;
        __sincosf(ang0, &s0, &c0);
        float c1 = c0 * ck - s0 * sk;
        float K2 = ck + ck;
        acc[0] = fmaf(a, c0, acc[0]);
        acc[1] = fmaf(a, c1, acc[1]);
#pragma unroll
        for (int j = 2; j < 16; ++j) {
            float c2 = fmaf(K2, c1, -c0);
            acc[j] = fmaf(a, c2, acc[j]);
            c0 = c1; c1 = c2;
        }
    }
    const float2 st = st_s[dl];
#pragma unroll
    for (int j = 0; j < 16; ++j) {
        float o = fmaf(acc[j], st.y, st.x);
        int t = tbase + j;
        out[((size_t)b * T_OUT + t) * D_DIM + d0 + dl] = o;
        if (t < 256)
            out[((size_t)b * T_OUT + t + 1024) * D_DIM + d0 + dl] = o;
    }
}

// ---------------------------------------------------------------------------
extern "C" void kernel_launch(void* const* d_in, const int* in_sizes, int n_in,
                              void* d_out, int out_size, void* d_ws, size_t ws_size,
                              hipStream_t stream) {
    const float* x = (const float*)d_in[0];
    float* out = (float*)d_out;
    char* ws = (char*)d_ws;
    const size_t MB = 1024 * 1024;

    // layout (total ~18.2 MB):
    float*   xt    = (float*)ws;                          // 16 MB
    double2* tw    = (double2*)(ws + 16 * MB);            // 16 KB
    float2*  stats = (float2*)(ws + 16 * MB + 65536);     // 32 KB
    float4*  sel   = (float4*)(ws + 16 * MB + 131072);    //  2 MB

    transpose_kernel<<<dim3(8, 16, 8), 256, 0, stream>>>(x, xt, tw);
    dft_kernel<<<NPAIR, 256, 0, stream>>>(xt, tw, stats, sel);
    recon_kernel<<<1024, 256, 0, stream>>>(sel, stats, out);
}